// Round 1
// baseline (1756.705 us; speedup 1.0000x reference)
//
#include <hip/hip_runtime.h>
#include <cstdint>
#include <cstddef>

#define N_ROWS 2048
#define C_DIM  1024
#define HW     64
#define NH     8
#define HD     128
#define NG     32
#define QKV_DIM 3072

// ---------------------------------------------------------------------------
// Group setup: counts, exclusive offsets, and rows sorted by group.
// Single block; order within a group is irrelevant (softmax is permutation
// invariant and outputs are scattered back per row).
// ---------------------------------------------------------------------------
__global__ __launch_bounds__(256) void group_setup(const int* __restrict__ bidx,
                                                   int* __restrict__ counts,
                                                   int* __restrict__ offsets,
                                                   int* __restrict__ sorted)
{
    __shared__ int scnt[NG];
    __shared__ int soff[NG];
    __shared__ int sfill[NG];
    int tid = threadIdx.x;
    if (tid < NG) scnt[tid] = 0;
    __syncthreads();
    for (int n = tid; n < N_ROWS; n += 256) atomicAdd(&scnt[bidx[n]], 1);
    __syncthreads();
    if (tid == 0) {
        int run = 0;
        for (int g = 0; g < NG; ++g) { soff[g] = run; run += scnt[g]; }
    }
    __syncthreads();
    if (tid < NG) { counts[tid] = scnt[tid]; offsets[tid] = soff[tid]; sfill[tid] = soff[tid]; }
    __syncthreads();
    for (int n = tid; n < N_ROWS; n += 256) {
        int pos = atomicAdd(&sfill[bidx[n]], 1);
        sorted[pos] = n;
    }
}

// ---------------------------------------------------------------------------
// feat[n][c] = mean over 64 contiguous floats of x.  One 16-lane subgroup per
// (n,c) pair; float4 loads -> 16 B/lane fully coalesced.
// ---------------------------------------------------------------------------
__global__ __launch_bounds__(256) void feat_mean(const float* __restrict__ x,
                                                 float* __restrict__ feat)
{
    int tid  = blockIdx.x * 256 + threadIdx.x;
    int gw   = tid >> 6;     // global wave id; covers 4 (n,c) pairs
    int lane = tid & 63;
    const float4 v = ((const float4*)x)[(size_t)gw * 64 + lane];
    float s = v.x + v.y + v.z + v.w;
    s += __shfl_xor(s, 1);
    s += __shfl_xor(s, 2);
    s += __shfl_xor(s, 4);
    s += __shfl_xor(s, 8);
    if ((lane & 15) == 0) feat[gw * 4 + (lane >> 4)] = s * (1.0f / 64.0f);
}

// ---------------------------------------------------------------------------
// In-place LayerNorm over C=1024.  One block per row.
// ---------------------------------------------------------------------------
__global__ __launch_bounds__(256) void layernorm(float* __restrict__ feat,
                                                 const float* __restrict__ w,
                                                 const float* __restrict__ b)
{
    int n = blockIdx.x, tid = threadIdx.x;
    float* row = feat + (size_t)n * C_DIM;
    float vals[4];
    float s1 = 0.f, s2 = 0.f;
    #pragma unroll
    for (int i = 0; i < 4; ++i) {
        float v = row[tid + i * 256];
        vals[i] = v; s1 += v; s2 += v * v;
    }
    #pragma unroll
    for (int m = 1; m < 64; m <<= 1) { s1 += __shfl_xor(s1, m); s2 += __shfl_xor(s2, m); }
    __shared__ float red[8];
    int wave = tid >> 6, lane = tid & 63;
    if (lane == 0) { red[wave] = s1; red[4 + wave] = s2; }
    __syncthreads();
    s1 = red[0] + red[1] + red[2] + red[3];
    s2 = red[4] + red[5] + red[6] + red[7];
    float mu  = s1 * (1.0f / C_DIM);
    float var = s2 * (1.0f / C_DIM) - mu * mu;
    float rs  = rsqrtf(var + 1e-5f);
    #pragma unroll
    for (int i = 0; i < 4; ++i) {
        int c = tid + i * 256;
        row[c] = (vals[i] - mu) * rs * w[c] + b[c];
    }
}

// ---------------------------------------------------------------------------
// C[M][Nc] = A[M][K] * B[Nc][K]^T + bias   (both operands K-contiguous).
// 128x128 block tile, BK=16, 256 threads, 8x8 outputs/thread, fp32 VALU.
// EPI==1: fused out_proj epilogue -> delta = (gemm+bias)*gamma*valid(row).
// ---------------------------------------------------------------------------
template<int EPI>
__global__ __launch_bounds__(256) void gemm_bt(
    const float* __restrict__ A, const float* __restrict__ B,
    const float* __restrict__ bias, float* __restrict__ C,
    int M, int Nc, int K,
    const float* __restrict__ gamma,
    const int* __restrict__ counts,
    const int* __restrict__ bidx)
{
    __shared__ float As[16][128];
    __shared__ float Bs[16][128];
    const int tid  = threadIdx.x;
    const int m0   = blockIdx.y * 128, n0 = blockIdx.x * 128;
    const int quad = tid & 3;     // which float4 along K
    const int lrow = tid >> 2;    // 0..63
    const int tc   = tid & 15;    // output col group
    const int tr   = tid >> 4;    // output row group
    float acc[8][8];
    #pragma unroll
    for (int i = 0; i < 8; ++i)
        #pragma unroll
        for (int j = 0; j < 8; ++j) acc[i][j] = 0.f;

    const float* Ap0 = A + (size_t)(m0 + lrow) * K + quad * 4;
    const float* Ap1 = Ap0 + (size_t)64 * K;
    const float* Bp0 = B + (size_t)(n0 + lrow) * K + quad * 4;
    const float* Bp1 = Bp0 + (size_t)64 * K;

    for (int kt = 0; kt < K; kt += 16) {
        float4 a0 = *(const float4*)(Ap0 + kt);
        float4 a1 = *(const float4*)(Ap1 + kt);
        float4 b0 = *(const float4*)(Bp0 + kt);
        float4 b1 = *(const float4*)(Bp1 + kt);
        __syncthreads();                       // previous tile's reads done
        int kq = quad * 4;
        As[kq+0][lrow] = a0.x; As[kq+1][lrow] = a0.y; As[kq+2][lrow] = a0.z; As[kq+3][lrow] = a0.w;
        As[kq+0][lrow+64] = a1.x; As[kq+1][lrow+64] = a1.y; As[kq+2][lrow+64] = a1.z; As[kq+3][lrow+64] = a1.w;
        Bs[kq+0][lrow] = b0.x; Bs[kq+1][lrow] = b0.y; Bs[kq+2][lrow] = b0.z; Bs[kq+3][lrow] = b0.w;
        Bs[kq+0][lrow+64] = b1.x; Bs[kq+1][lrow+64] = b1.y; Bs[kq+2][lrow+64] = b1.z; Bs[kq+3][lrow+64] = b1.w;
        __syncthreads();
        #pragma unroll
        for (int kk = 0; kk < 16; ++kk) {
            float ar[8], br[8];
            *(float4*)(ar)     = *(const float4*)&As[kk][tr * 8];
            *(float4*)(ar + 4) = *(const float4*)&As[kk][tr * 8 + 4];
            *(float4*)(br)     = *(const float4*)&Bs[kk][tc * 8];
            *(float4*)(br + 4) = *(const float4*)&Bs[kk][tc * 8 + 4];
            #pragma unroll
            for (int i = 0; i < 8; ++i)
                #pragma unroll
                for (int j = 0; j < 8; ++j)
                    acc[i][j] = fmaf(ar[i], br[j], acc[i][j]);
        }
    }
    #pragma unroll
    for (int i = 0; i < 8; ++i) {
        int m = m0 + tr * 8 + i;
        float g = 1.0f;
        if (EPI == 1) g = (counts[bidx[m]] > 1) ? gamma[0] : 0.0f;
        #pragma unroll
        for (int j = 0; j < 8; ++j) {
            int n = n0 + tc * 8 + j;
            float v = acc[i][j] + bias[n];
            if (EPI == 1) v *= g;
            C[(size_t)m * Nc + n] = v;
        }
    }
}

// ---------------------------------------------------------------------------
// Block-diagonal attention.  One block per (group, head); K/V staged in LDS
// in 64-row tiles; each wave owns one q-row at a time; online softmax.
// All __syncthreads() in uniform control flow (loop bounds are group-wide).
// ---------------------------------------------------------------------------
__global__ __launch_bounds__(256) void attn_kernel(
    const float* __restrict__ qkv, const int* __restrict__ sorted,
    const int* __restrict__ offsets, const int* __restrict__ counts,
    float* __restrict__ attn_out)
{
    const int g = blockIdx.x, h = blockIdx.y;
    const int cnt = counts[g], off = offsets[g];
    if (cnt == 0) return;
    __shared__ float kt[64][128];
    __shared__ float vt[64][128];
    const int tid = threadIdx.x;
    const int wave = tid >> 6, lane = tid & 63;
    const float scale = 0.08838834764831845f;   // 1/sqrt(128)
    const int nChunks = (cnt + 3) / 4;
    const int nTiles  = (cnt + 63) / 64;
    for (int qc = 0; qc < nChunks; ++qc) {
        int  qi   = qc * 4 + wave;
        bool havq = qi < cnt;
        int  qrow = havq ? sorted[off + qi] : 0;
        const float* qp = qkv + (size_t)qrow * QKV_DIM + h * HD;
        float2 qv = *(const float2*)(qp + 2 * lane);
        float mrun = -3.0e38f, lrun = 0.f, acc0 = 0.f, acc1 = 0.f;
        for (int t = 0; t < nTiles; ++t) {
            __syncthreads();                    // prior reads of kt/vt done
            int tbase = t * 64;
            int trows = min(64, cnt - tbase);
            #pragma unroll
            for (int it = 0; it < 8; ++it) {
                int fi = tid + it * 256;        // float4 index within tile
                int r  = fi >> 5;
                int cq = fi & 31;
                if (r < trows) {
                    int nrow = sorted[off + tbase + r];
                    const float* kp = qkv + (size_t)nrow * QKV_DIM + C_DIM + h * HD;
                    const float* vp = qkv + (size_t)nrow * QKV_DIM + 2 * C_DIM + h * HD;
                    *(float4*)&kt[r][cq * 4] = *(const float4*)(kp + cq * 4);
                    *(float4*)&vt[r][cq * 4] = *(const float4*)(vp + cq * 4);
                }
            }
            __syncthreads();
            if (havq) {
                for (int j = 0; j < trows; ++j) {
                    float sp = qv.x * kt[j][2 * lane] + qv.y * kt[j][2 * lane + 1];
                    #pragma unroll
                    for (int m = 1; m < 64; m <<= 1) sp += __shfl_xor(sp, m);
                    float s  = sp * scale;
                    float nm = fmaxf(mrun, s);
                    float alpha = __expf(mrun - nm);
                    float e     = __expf(s - nm);
                    lrun = lrun * alpha + e;
                    acc0 = acc0 * alpha + e * vt[j][2 * lane];
                    acc1 = acc1 * alpha + e * vt[j][2 * lane + 1];
                    mrun = nm;
                }
            }
        }
        if (havq) {
            float inv = 1.0f / lrun;
            float* op = attn_out + (size_t)qrow * C_DIM + h * HD;
            float2 o; o.x = acc0 * inv; o.y = acc1 * inv;
            *(float2*)(op + 2 * lane) = o;
        }
    }
}

// ---------------------------------------------------------------------------
// y[n][c][hw] = x[n][c][hw] + delta[n][c]   (delta already gamma*valid-scaled)
// ---------------------------------------------------------------------------
__global__ __launch_bounds__(256) void final_add(
    const float* __restrict__ x, const float* __restrict__ delta,
    float* __restrict__ out)
{
    size_t i = (size_t)blockIdx.x * 256 + threadIdx.x;   // float4 index
    float4 xv = ((const float4*)x)[i];
    float  d  = delta[i >> 4];                            // 16 float4 per (n,c)
    float4 o;
    o.x = xv.x + d; o.y = xv.y + d; o.z = xv.z + d; o.w = xv.w + d;
    ((float4*)out)[i] = o;
}

// ---------------------------------------------------------------------------
extern "C" void kernel_launch(void* const* d_in, const int* in_sizes, int n_in,
                              void* d_out, int out_size, void* d_ws, size_t ws_size,
                              hipStream_t stream)
{
    const float* x          = (const float*)d_in[0];
    const int*   bidx       = (const int*)d_in[1];
    const float* ln_w       = (const float*)d_in[2];
    const float* ln_b       = (const float*)d_in[3];
    const float* in_proj_w  = (const float*)d_in[4];
    const float* in_proj_b  = (const float*)d_in[5];
    const float* out_proj_w = (const float*)d_in[6];
    const float* out_proj_b = (const float*)d_in[7];
    const float* gamma      = (const float*)d_in[8];
    float* out = (float*)d_out;

    float* ws       = (float*)d_ws;
    float* feat     = ws;                                  // 2M floats
    float* qkv      = ws + (size_t)2  * 1024 * 1024;       // 6M floats
    float* attn_out = ws + (size_t)8  * 1024 * 1024;       // 2M floats
    float* delta    = ws + (size_t)10 * 1024 * 1024;       // 2M floats
    int*   ints     = (int*)(ws + (size_t)12 * 1024 * 1024);
    int*   counts   = ints;                                // 32
    int*   offsets  = ints + 32;                           // 32
    int*   sorted   = ints + 64;                           // 2048

    group_setup<<<dim3(1), dim3(256), 0, stream>>>(bidx, counts, offsets, sorted);
    feat_mean<<<dim3(131072), dim3(256), 0, stream>>>(x, feat);
    layernorm<<<dim3(2048), dim3(256), 0, stream>>>(feat, ln_w, ln_b);
    gemm_bt<0><<<dim3(24, 16), dim3(256), 0, stream>>>(
        feat, in_proj_w, in_proj_b, qkv, 2048, 3072, 1024, nullptr, nullptr, nullptr);
    attn_kernel<<<dim3(32, 8), dim3(256), 0, stream>>>(qkv, sorted, offsets, counts, attn_out);
    gemm_bt<1><<<dim3(8, 16), dim3(256), 0, stream>>>(
        attn_out, out_proj_w, out_proj_b, delta, 2048, 1024, 1024, gamma, counts, bidx);
    final_add<<<dim3(131072), dim3(256), 0, stream>>>(x, delta, out);
}